// Round 12
// baseline (3499.432 us; speedup 1.0000x reference)
//
#include <hip/hip_runtime.h>

#define B_ROWS  8192
#define IN_DIM  4096
#define OUT_DIM 4096

#define BM 64
#define BN 64
#define BK 16
#define TILES (IN_DIM / BK)   // 256 tiles of 16
// Hypothesis: referee BLAS = AOCL-BLIS zen3/4/5 class, KC=512.
// BLIS K-loop: plain KC blocks, no tail halving -> 8 exact blocks of 512.
// Flush every 32 BK-tiles (k = 512,1024,...,4096).
#define LDS_A 68   // stride (floats) for As[BK][BM] transposed tile; float4-aligned
#define LDS_B 68   // stride (floats) for Bs[BK][BN]

// GEMM C = X*W + b emulating kc=512-blocked CPU sgemm rounding:
// per kc block a single sequential f32 FMA chain (ascending k, acc from 0);
// block partials combined left-associated with plain f32 adds.
// Fused VQ epilogue in reference-exact f32.
__global__ __launch_bounds__(256) void vq_fused_gemm(
    const float* __restrict__ X, const float* __restrict__ Wm,
    const float* __restrict__ bvec, const float* __restrict__ emb,
    float* __restrict__ out_idx, float* __restrict__ out_q, float* __restrict__ out_ze)
{
    __shared__ float As[BK * LDS_A];   // As[k][row]  (transposed A tile)
    __shared__ float Bs[BK * LDS_B];   // Bs[k][col]

    const int tid  = threadIdx.x;        // 0..255
    const int tx   = tid & 15;           // output col group (4 cols each)
    const int ty   = tid >> 4;           // output row group (4 rows each)
    const int brow = blockIdx.y * BM;
    const int bcol = blockIdx.x * BN;

    // staging assignments
    const int a_row = tid >> 2;          // 0..63
    const int a_k   = (tid & 3) << 2;    // 0,4,8,12
    const int b_k   = tid >> 4;          // 0..15
    const int b_col = (tid & 15) << 2;   // 0..60

    const float* Aptr = X  + (size_t)(brow + a_row) * IN_DIM + a_k;
    const float* Bptr = Wm + (size_t)b_k * OUT_DIM + bcol + b_col;

    float acc_tot[4][4];   // running C (left-associated sum of kc-block partials)
    float acc_blk[4][4];   // current kc-block partial (sequential FMA chain)
    #pragma unroll
    for (int i = 0; i < 4; ++i)
        #pragma unroll
        for (int j = 0; j < 4; ++j) { acc_tot[i][j] = 0.0f; acc_blk[i][j] = 0.0f; }

    for (int t = 0; t < TILES; ++t) {
        const int k0 = t * BK;
        float4 av = *reinterpret_cast<const float4*>(Aptr + k0);
        float4 bv = *reinterpret_cast<const float4*>(Bptr + (size_t)k0 * OUT_DIM);
        __syncthreads();   // previous tile fully consumed before overwrite
        As[(a_k + 0) * LDS_A + a_row] = av.x;
        As[(a_k + 1) * LDS_A + a_row] = av.y;
        As[(a_k + 2) * LDS_A + a_row] = av.z;
        As[(a_k + 3) * LDS_A + a_row] = av.w;
        *reinterpret_cast<float4*>(&Bs[b_k * LDS_B + b_col]) = bv;
        __syncthreads();

        #pragma unroll
        for (int kk = 0; kk < BK; ++kk) {
            float4 af = *reinterpret_cast<const float4*>(&As[kk * LDS_A + ty * 4]);
            float4 bf = *reinterpret_cast<const float4*>(&Bs[kk * LDS_B + tx * 4]);
            acc_blk[0][0] = fmaf(af.x, bf.x, acc_blk[0][0]);
            acc_blk[0][1] = fmaf(af.x, bf.y, acc_blk[0][1]);
            acc_blk[0][2] = fmaf(af.x, bf.z, acc_blk[0][2]);
            acc_blk[0][3] = fmaf(af.x, bf.w, acc_blk[0][3]);
            acc_blk[1][0] = fmaf(af.y, bf.x, acc_blk[1][0]);
            acc_blk[1][1] = fmaf(af.y, bf.y, acc_blk[1][1]);
            acc_blk[1][2] = fmaf(af.y, bf.z, acc_blk[1][2]);
            acc_blk[1][3] = fmaf(af.y, bf.w, acc_blk[1][3]);
            acc_blk[2][0] = fmaf(af.z, bf.x, acc_blk[2][0]);
            acc_blk[2][1] = fmaf(af.z, bf.y, acc_blk[2][1]);
            acc_blk[2][2] = fmaf(af.z, bf.z, acc_blk[2][2]);
            acc_blk[2][3] = fmaf(af.z, bf.w, acc_blk[2][3]);
            acc_blk[3][0] = fmaf(af.w, bf.x, acc_blk[3][0]);
            acc_blk[3][1] = fmaf(af.w, bf.y, acc_blk[3][1]);
            acc_blk[3][2] = fmaf(af.w, bf.z, acc_blk[3][2]);
            acc_blk[3][3] = fmaf(af.w, bf.w, acc_blk[3][3]);
        }

        // kc=512 flush boundaries: every 32 tiles (k = 512,1024,...,4096)
        const int done = t + 1;
        if ((done & 31) == 0) {
            #pragma unroll
            for (int i = 0; i < 4; ++i)
                #pragma unroll
                for (int j = 0; j < 4; ++j) {
                    acc_tot[i][j] = acc_tot[i][j] + acc_blk[i][j];  // plain f32 add
                    acc_blk[i][j] = 0.0f;
                }
        }
    }

    // epilogue: reference-exact f32 arithmetic, f32 outputs
    const int c0 = bcol + tx * 4;
    float e0c[4], e1c[4], bb[4];
    #pragma unroll
    for (int j = 0; j < 4; ++j) {
        e0c[j] = emb[2 * (c0 + j) + 0];
        e1c[j] = emb[2 * (c0 + j) + 1];
        bb[j]  = bvec[c0 + j];
    }

    #pragma unroll
    for (int i = 0; i < 4; ++i) {
        const int r = brow + ty * 4 + i;
        float4 vidx, vq, vz;
        float* pi = (float*)&vidx;
        float* pq = (float*)&vq;
        float* pz = (float*)&vz;
        #pragma unroll
        for (int j = 0; j < 4; ++j) {
            float zb    = acc_tot[i][j] + bb[j];  // z_e = dot + b (f32 add; b==0)
            float diff0 = zb - e0c[j];
            float diff1 = zb - e1c[j];
            float d0    = diff0 * diff0;          // f32 mul, no fma
            float d1    = diff1 * diff1;
            int   idx   = (d1 < d0) ? 1 : 0;      // argmin, ties -> 0 (first)
            float qf    = idx ? e1c[j] : e0c[j];
            pi[j] = (float)idx;
            pq[j] = zb + (qf - zb);               // quantized_st as in reference
            pz[j] = zb;
        }
        size_t off = (size_t)r * OUT_DIM + c0;
        *reinterpret_cast<float4*>(&out_idx[off]) = vidx;
        *reinterpret_cast<float4*>(&out_q[off])   = vq;
        *reinterpret_cast<float4*>(&out_ze[off])  = vz;
    }
}

__global__ void copy_emb(const float* __restrict__ emb, float* __restrict__ out, int n)
{
    int i = blockIdx.x * blockDim.x + threadIdx.x;
    if (i < n) out[i] = emb[i];
}

extern "C" void kernel_launch(void* const* d_in, const int* in_sizes, int n_in,
                              void* d_out, int out_size, void* d_ws, size_t ws_size,
                              hipStream_t stream)
{
    const float* X   = (const float*)d_in[0];
    const float* W   = (const float*)d_in[1];
    const float* b   = (const float*)d_in[2];
    const float* emb = (const float*)d_in[3];

    float* out = (float*)d_out;
    const size_t n_big = (size_t)B_ROWS * OUT_DIM;   // 33,554,432
    float* out_idx = out;
    float* out_emb = out + n_big;
    float* out_q   = out_emb + (size_t)OUT_DIM * 2;
    float* out_ze  = out_q + n_big;

    dim3 grid(OUT_DIM / BN, B_ROWS / BM);
    vq_fused_gemm<<<grid, dim3(256), 0, stream>>>(X, W, b, emb, out_idx, out_q, out_ze);

    int nemb = OUT_DIM * 2;
    copy_emb<<<(nemb + 255) / 256, 256, 0, stream>>>(emb, out_emb, nemb);
}

// Round 13
// 3495.440 us; speedup vs baseline: 1.0011x; 1.0011x over previous
//
#include <hip/hip_runtime.h>

#define B_ROWS  8192
#define IN_DIM  4096
#define OUT_DIM 4096

#define BM 64
#define BN 64
#define BK 16
#define TILES (IN_DIM / BK)   // 256 tiles of 16
// Hypothesis: referee BLAS = AOCL-BLIS zen3/4/5 class, KC=512.
// BLIS K-loop: plain KC blocks, no tail halving -> 8 exact blocks of 512.
// Flush every 32 BK-tiles (k = 512,1024,...,4096).
#define LDS_A 68   // stride (floats) for As[BK][BM] transposed tile; float4-aligned
#define LDS_B 68   // stride (floats) for Bs[BK][BN]

// GEMM C = X*W + b emulating kc=512-blocked CPU sgemm rounding:
// per kc block a single sequential f32 FMA chain (ascending k, acc from 0);
// block partials combined left-associated with plain f32 adds.
// Fused VQ epilogue in reference-exact f32.
__global__ __launch_bounds__(256) void vq_fused_gemm(
    const float* __restrict__ X, const float* __restrict__ Wm,
    const float* __restrict__ bvec, const float* __restrict__ emb,
    float* __restrict__ out_idx, float* __restrict__ out_q, float* __restrict__ out_ze)
{
    __shared__ float As[BK * LDS_A];   // As[k][row]  (transposed A tile)
    __shared__ float Bs[BK * LDS_B];   // Bs[k][col]

    const int tid  = threadIdx.x;        // 0..255
    const int tx   = tid & 15;           // output col group (4 cols each)
    const int ty   = tid >> 4;           // output row group (4 rows each)
    const int brow = blockIdx.y * BM;
    const int bcol = blockIdx.x * BN;

    // staging assignments
    const int a_row = tid >> 2;          // 0..63
    const int a_k   = (tid & 3) << 2;    // 0,4,8,12
    const int b_k   = tid >> 4;          // 0..15
    const int b_col = (tid & 15) << 2;   // 0..60

    const float* Aptr = X  + (size_t)(brow + a_row) * IN_DIM + a_k;
    const float* Bptr = Wm + (size_t)b_k * OUT_DIM + bcol + b_col;

    float acc_tot[4][4];   // running C (left-associated sum of kc-block partials)
    float acc_blk[4][4];   // current kc-block partial (sequential FMA chain)
    #pragma unroll
    for (int i = 0; i < 4; ++i)
        #pragma unroll
        for (int j = 0; j < 4; ++j) { acc_tot[i][j] = 0.0f; acc_blk[i][j] = 0.0f; }

    for (int t = 0; t < TILES; ++t) {
        const int k0 = t * BK;
        float4 av = *reinterpret_cast<const float4*>(Aptr + k0);
        float4 bv = *reinterpret_cast<const float4*>(Bptr + (size_t)k0 * OUT_DIM);
        __syncthreads();   // previous tile fully consumed before overwrite
        As[(a_k + 0) * LDS_A + a_row] = av.x;
        As[(a_k + 1) * LDS_A + a_row] = av.y;
        As[(a_k + 2) * LDS_A + a_row] = av.z;
        As[(a_k + 3) * LDS_A + a_row] = av.w;
        *reinterpret_cast<float4*>(&Bs[b_k * LDS_B + b_col]) = bv;
        __syncthreads();

        #pragma unroll
        for (int kk = 0; kk < BK; ++kk) {
            float4 af = *reinterpret_cast<const float4*>(&As[kk * LDS_A + ty * 4]);
            float4 bf = *reinterpret_cast<const float4*>(&Bs[kk * LDS_B + tx * 4]);
            acc_blk[0][0] = fmaf(af.x, bf.x, acc_blk[0][0]);
            acc_blk[0][1] = fmaf(af.x, bf.y, acc_blk[0][1]);
            acc_blk[0][2] = fmaf(af.x, bf.z, acc_blk[0][2]);
            acc_blk[0][3] = fmaf(af.x, bf.w, acc_blk[0][3]);
            acc_blk[1][0] = fmaf(af.y, bf.x, acc_blk[1][0]);
            acc_blk[1][1] = fmaf(af.y, bf.y, acc_blk[1][1]);
            acc_blk[1][2] = fmaf(af.y, bf.z, acc_blk[1][2]);
            acc_blk[1][3] = fmaf(af.y, bf.w, acc_blk[1][3]);
            acc_blk[2][0] = fmaf(af.z, bf.x, acc_blk[2][0]);
            acc_blk[2][1] = fmaf(af.z, bf.y, acc_blk[2][1]);
            acc_blk[2][2] = fmaf(af.z, bf.z, acc_blk[2][2]);
            acc_blk[2][3] = fmaf(af.z, bf.w, acc_blk[2][3]);
            acc_blk[3][0] = fmaf(af.w, bf.x, acc_blk[3][0]);
            acc_blk[3][1] = fmaf(af.w, bf.y, acc_blk[3][1]);
            acc_blk[3][2] = fmaf(af.w, bf.z, acc_blk[3][2]);
            acc_blk[3][3] = fmaf(af.w, bf.w, acc_blk[3][3]);
        }

        // kc=512 flush boundaries: every 32 tiles (k = 512,1024,...,4096)
        const int done = t + 1;
        if ((done & 31) == 0) {
            #pragma unroll
            for (int i = 0; i < 4; ++i)
                #pragma unroll
                for (int j = 0; j < 4; ++j) {
                    acc_tot[i][j] = acc_tot[i][j] + acc_blk[i][j];  // plain f32 add
                    acc_blk[i][j] = 0.0f;
                }
        }
    }

    // epilogue: reference-exact f32 arithmetic, f32 outputs
    const int c0 = bcol + tx * 4;
    float e0c[4], e1c[4], bb[4];
    #pragma unroll
    for (int j = 0; j < 4; ++j) {
        e0c[j] = emb[2 * (c0 + j) + 0];
        e1c[j] = emb[2 * (c0 + j) + 1];
        bb[j]  = bvec[c0 + j];
    }

    #pragma unroll
    for (int i = 0; i < 4; ++i) {
        const int r = brow + ty * 4 + i;
        float4 vidx, vq, vz;
        float* pi = (float*)&vidx;
        float* pq = (float*)&vq;
        float* pz = (float*)&vz;
        #pragma unroll
        for (int j = 0; j < 4; ++j) {
            float zb    = acc_tot[i][j] + bb[j];  // z_e = dot + b (f32 add; b==0)
            float diff0 = zb - e0c[j];
            float diff1 = zb - e1c[j];
            float d0    = diff0 * diff0;          // f32 mul, no fma
            float d1    = diff1 * diff1;
            int   idx   = (d1 < d0) ? 1 : 0;      // argmin, ties -> 0 (first)
            float qf    = idx ? e1c[j] : e0c[j];
            pi[j] = (float)idx;
            pq[j] = zb + (qf - zb);               // quantized_st as in reference
            pz[j] = zb;
        }
        size_t off = (size_t)r * OUT_DIM + c0;
        *reinterpret_cast<float4*>(&out_idx[off]) = vidx;
        *reinterpret_cast<float4*>(&out_q[off])   = vq;
        *reinterpret_cast<float4*>(&out_ze[off])  = vz;
    }
}

__global__ void copy_emb(const float* __restrict__ emb, float* __restrict__ out, int n)
{
    int i = blockIdx.x * blockDim.x + threadIdx.x;
    if (i < n) out[i] = emb[i];
}

extern "C" void kernel_launch(void* const* d_in, const int* in_sizes, int n_in,
                              void* d_out, int out_size, void* d_ws, size_t ws_size,
                              hipStream_t stream)
{
    const float* X   = (const float*)d_in[0];
    const float* W   = (const float*)d_in[1];
    const float* b   = (const float*)d_in[2];
    const float* emb = (const float*)d_in[3];

    float* out = (float*)d_out;
    const size_t n_big = (size_t)B_ROWS * OUT_DIM;   // 33,554,432
    float* out_idx = out;
    float* out_emb = out + n_big;
    float* out_q   = out_emb + (size_t)OUT_DIM * 2;
    float* out_ze  = out_q + n_big;

    dim3 grid(OUT_DIM / BN, B_ROWS / BM);
    vq_fused_gemm<<<grid, dim3(256), 0, stream>>>(X, W, b, emb, out_idx, out_q, out_ze);

    int nemb = OUT_DIM * 2;
    copy_emb<<<(nemb + 255) / 256, 256, 0, stream>>>(emb, out_emb, nemb);
}

// Round 14
// 3386.363 us; speedup vs baseline: 1.0334x; 1.0322x over previous
//
#include <hip/hip_runtime.h>

#define B_ROWS  8192
#define IN_DIM  4096
#define OUT_DIM 4096

#define BM 128
#define BN 128
#define BK 16
#define TILES (IN_DIM / BK)   // 256 tiles of 16
// Referee BLAS (verified R13): kc=512 blocking, 8 exact blocks.
// Flush every 32 BK-tiles (k = 512,1024,...,4096).
#define PADA 132   // stride (floats) for As[BK][BM] transposed tile
#define PADB 132   // stride (floats) for Bs[BK][BN]

// GEMM C = X*W + b emulating kc=512-blocked CPU sgemm rounding:
// per kc block a single sequential f32 FMA chain (ascending k, acc from 0);
// block partials combined left-associated with plain f32 adds.
// Fused VQ epilogue in reference-exact f32.
// 128x128 tile, 8x8/thread as 2x2 groups of 4x4 at +-64 offsets.
__global__ __launch_bounds__(256, 2) void vq_fused_gemm(
    const float* __restrict__ X, const float* __restrict__ Wm,
    const float* __restrict__ bvec, const float* __restrict__ emb,
    float* __restrict__ out_idx, float* __restrict__ out_q, float* __restrict__ out_ze)
{
    __shared__ float As[BK * PADA];   // As[k][row]  (transposed A tile)
    __shared__ float Bs[BK * PADB];   // Bs[k][col]

    const int tid  = threadIdx.x;        // 0..255
    const int tx   = tid & 15;           // col group: cols tx*4..+3 and 64+tx*4..+3
    const int ty   = tid >> 4;           // row group: rows ty*4..+3 and 64+ty*4..+3
    const int brow = blockIdx.y * BM;
    const int bcol = blockIdx.x * BN;

    // staging assignments
    const int a_row = tid >> 1;          // 0..127
    const int a_k   = (tid & 1) << 3;    // 0 or 8
    const int b_k   = tid >> 4;          // 0..15
    const int b_col = (tid & 15) << 3;   // 0,8,...,120

    const float* Aptr = X  + (size_t)(brow + a_row) * IN_DIM + a_k;
    const float* Bptr = Wm + (size_t)b_k * OUT_DIM + bcol + b_col;

    // acc[im][jm][i][j]: element (row im*64+ty*4+i, col jm*64+tx*4+j)
    float acc_tot[2][2][4][4];   // running C (left-assoc sum of kc partials)
    float acc_blk[2][2][4][4];   // current kc-block partial (sequential chain)
    #pragma unroll
    for (int im = 0; im < 2; ++im)
        #pragma unroll
        for (int jm = 0; jm < 2; ++jm)
            #pragma unroll
            for (int i = 0; i < 4; ++i)
                #pragma unroll
                for (int j = 0; j < 4; ++j) {
                    acc_tot[im][jm][i][j] = 0.0f;
                    acc_blk[im][jm][i][j] = 0.0f;
                }

    for (int t = 0; t < TILES; ++t) {
        const int k0 = t * BK;
        float4 av0 = *reinterpret_cast<const float4*>(Aptr + k0);
        float4 av1 = *reinterpret_cast<const float4*>(Aptr + k0 + 4);
        float4 bv0 = *reinterpret_cast<const float4*>(Bptr + (size_t)k0 * OUT_DIM);
        float4 bv1 = *reinterpret_cast<const float4*>(Bptr + (size_t)k0 * OUT_DIM + 4);
        __syncthreads();   // previous tile fully consumed before overwrite
        As[(a_k + 0) * PADA + a_row] = av0.x;
        As[(a_k + 1) * PADA + a_row] = av0.y;
        As[(a_k + 2) * PADA + a_row] = av0.z;
        As[(a_k + 3) * PADA + a_row] = av0.w;
        As[(a_k + 4) * PADA + a_row] = av1.x;
        As[(a_k + 5) * PADA + a_row] = av1.y;
        As[(a_k + 6) * PADA + a_row] = av1.z;
        As[(a_k + 7) * PADA + a_row] = av1.w;
        *reinterpret_cast<float4*>(&Bs[b_k * PADB + b_col])     = bv0;
        *reinterpret_cast<float4*>(&Bs[b_k * PADB + b_col + 4]) = bv1;
        __syncthreads();

        #pragma unroll
        for (int kk = 0; kk < BK; ++kk) {
            float4 a0 = *reinterpret_cast<const float4*>(&As[kk * PADA + ty * 4]);
            float4 a1 = *reinterpret_cast<const float4*>(&As[kk * PADA + 64 + ty * 4]);
            float4 b0 = *reinterpret_cast<const float4*>(&Bs[kk * PADB + tx * 4]);
            float4 b1 = *reinterpret_cast<const float4*>(&Bs[kk * PADB + 64 + tx * 4]);
            const float* ap[2] = { (const float*)&a0, (const float*)&a1 };
            const float* bp[2] = { (const float*)&b0, (const float*)&b1 };
            #pragma unroll
            for (int im = 0; im < 2; ++im)
                #pragma unroll
                for (int jm = 0; jm < 2; ++jm)
                    #pragma unroll
                    for (int i = 0; i < 4; ++i)
                        #pragma unroll
                        for (int j = 0; j < 4; ++j)
                            acc_blk[im][jm][i][j] =
                                fmaf(ap[im][i], bp[jm][j], acc_blk[im][jm][i][j]);
        }

        // kc=512 flush boundaries: every 32 tiles (k = 512,1024,...,4096)
        if (((t + 1) & 31) == 0) {
            #pragma unroll
            for (int im = 0; im < 2; ++im)
                #pragma unroll
                for (int jm = 0; jm < 2; ++jm)
                    #pragma unroll
                    for (int i = 0; i < 4; ++i)
                        #pragma unroll
                        for (int j = 0; j < 4; ++j) {
                            acc_tot[im][jm][i][j] += acc_blk[im][jm][i][j]; // plain add
                            acc_blk[im][jm][i][j] = 0.0f;
                        }
        }
    }

    // epilogue: reference-exact f32 arithmetic, f32 outputs
    float e0c[2][4], e1c[2][4], bb[2][4];
    #pragma unroll
    for (int jm = 0; jm < 2; ++jm) {
        const int cb = bcol + jm * 64 + tx * 4;
        #pragma unroll
        for (int j = 0; j < 4; ++j) {
            e0c[jm][j] = emb[2 * (cb + j) + 0];
            e1c[jm][j] = emb[2 * (cb + j) + 1];
            bb[jm][j]  = bvec[cb + j];
        }
    }

    #pragma unroll
    for (int im = 0; im < 2; ++im)
        #pragma unroll
        for (int i = 0; i < 4; ++i) {
            const int r = brow + im * 64 + ty * 4 + i;
            #pragma unroll
            for (int jm = 0; jm < 2; ++jm) {
                float4 vidx, vq, vz;
                float* pi = (float*)&vidx;
                float* pq = (float*)&vq;
                float* pz = (float*)&vz;
                #pragma unroll
                for (int j = 0; j < 4; ++j) {
                    float zb    = acc_tot[im][jm][i][j] + bb[jm][j]; // f32 add (b==0)
                    float diff0 = zb - e0c[jm][j];
                    float diff1 = zb - e1c[jm][j];
                    float d0    = diff0 * diff0;      // f32 mul, no fma
                    float d1    = diff1 * diff1;
                    int   idx   = (d1 < d0) ? 1 : 0;  // argmin, ties -> 0 (first)
                    float qf    = idx ? e1c[jm][j] : e0c[jm][j];
                    pi[j] = (float)idx;
                    pq[j] = zb + (qf - zb);           // quantized_st as in reference
                    pz[j] = zb;
                }
                size_t off = (size_t)r * OUT_DIM + bcol + jm * 64 + tx * 4;
                *reinterpret_cast<float4*>(&out_idx[off]) = vidx;
                *reinterpret_cast<float4*>(&out_q[off])   = vq;
                *reinterpret_cast<float4*>(&out_ze[off])  = vz;
            }
        }
}

__global__ void copy_emb(const float* __restrict__ emb, float* __restrict__ out, int n)
{
    int i = blockIdx.x * blockDim.x + threadIdx.x;
    if (i < n) out[i] = emb[i];
}

extern "C" void kernel_launch(void* const* d_in, const int* in_sizes, int n_in,
                              void* d_out, int out_size, void* d_ws, size_t ws_size,
                              hipStream_t stream)
{
    const float* X   = (const float*)d_in[0];
    const float* W   = (const float*)d_in[1];
    const float* b   = (const float*)d_in[2];
    const float* emb = (const float*)d_in[3];

    float* out = (float*)d_out;
    const size_t n_big = (size_t)B_ROWS * OUT_DIM;   // 33,554,432
    float* out_idx = out;
    float* out_emb = out + n_big;
    float* out_q   = out_emb + (size_t)OUT_DIM * 2;
    float* out_ze  = out_q + n_big;

    dim3 grid(OUT_DIM / BN, B_ROWS / BM);
    vq_fused_gemm<<<grid, dim3(256), 0, stream>>>(X, W, b, emb, out_idx, out_q, out_ze);

    int nemb = OUT_DIM * 2;
    copy_emb<<<(nemb + 255) / 256, 256, 0, stream>>>(emb, out_emb, nemb);
}